// Round 11
// baseline (558.253 us; speedup 1.0000x reference)
//
#include <hip/hip_runtime.h>
#include <hip/hip_bf16.h>

// Problem constants (fixed by setup_inputs)
constexpr int B_ = 64, L_ = 512, H_ = 768, T_ = 256, S_ = 128, D_ = 8;
constexpr int N_ = B_ * S_;        // 8192 nodes
constexpr int E0_ = 16 * N_;       // 131072 random edges
constexpr int NE_ = E0_ + N_;      // + self loops = 139264
constexpr float NEG_SLOPE = 0.2f;
constexpr int KDIM = 768;          // GEMM K (= H_)
constexpr int NB_WT = 3 * 576;     // W-transpose blocks
constexpr int NB_ZERO = 63;        // zero-fill blocks (63*4096 B = 258048 B)
constexpr int NB_QF = 512;         // qf partial blocks (b*8+chunk)

typedef __attribute__((ext_vector_type(8))) short short8v;
typedef __attribute__((ext_vector_type(4))) float f32x4;

#define GLOAD_LDS16(g, l) __builtin_amdgcn_global_load_lds( \
    (const __attribute__((address_space(1))) void*)(g), \
    (__attribute__((address_space(3))) void*)(l), 16, 0, 0)

__device__ __forceinline__ float bf2f(short s) {
  unsigned u = ((unsigned)(unsigned short)s) << 16;
  return __builtin_bit_cast(float, u);
}
__device__ __forceinline__ short f2bf(float f) {
  return (short)__bfloat16_as_ushort(__float2bfloat16(f));
}
__device__ __forceinline__ int docof(int b, const int* __restrict__ doc_spans) {
  int cnt = 0;
  for (int dd = 0; dd < D_; dd++) cnt += (doc_spans[dd * 2] <= b) ? 1 : 0;
  return cnt - 1;
}
__device__ __forceinline__ float aload(const float* p) {
  return __hip_atomic_load(p, __ATOMIC_RELAXED, __HIP_MEMORY_SCOPE_AGENT);
}

// -- dispatch 1: token pooling | W transpose | zero-fill | qf partials ------
__global__ __launch_bounds__(256) void k_prep(const float* __restrict__ features,
                                              const int* __restrict__ token_spans,
                                              const int* __restrict__ masks,
                                              const int* __restrict__ selidx,
                                              __hip_bfloat16* __restrict__ h0,
                                              const float* __restrict__ W0,
                                              const float* __restrict__ W1,
                                              const float* __restrict__ W2,
                                              __hip_bfloat16* __restrict__ Wt,
                                              int4* __restrict__ zero_base,
                                              const int* __restrict__ segment_ids,
                                              const int* __restrict__ is_head,
                                              float* __restrict__ qpart) {
  int bid = blockIdx.x;
  if (bid < N_) {
    // ---- token pooling: one block per node, 192 active lanes ----
    if (threadIdx.x >= 192) return;
    int n = bid;
    int b = n / S_;
    int t = selidx[n];
    int st = token_spans[(b * T_ + t) * 2 + 0];
    int en = token_spans[(b * T_ + t) * 2 + 1];
    int tid = threadIdx.x;
    float4 a = make_float4(0.f, 0.f, 0.f, 0.f);
    int cnt = 0;
    for (int l = st; l < en; l++) {
      if (masks[b * L_ + l] > 0) {
        cnt++;
        float4 v = ((const float4*)(features + ((size_t)b * L_ + l) * H_))[tid];
        a.x += v.x; a.y += v.y; a.z += v.z; a.w += v.w;
      }
    }
    float sc = (en > 0) ? (1.0f / (float)max(cnt, 1)) : 0.0f;
    short4 o;
    o.x = f2bf(a.x * sc); o.y = f2bf(a.y * sc); o.z = f2bf(a.z * sc); o.w = f2bf(a.w * sc);
    ((short4*)(h0 + (size_t)n * H_))[tid] = o;
    return;
  }
  if (bid < N_ + NB_WT) {
    // ---- W transpose + bf16: Wt[layer][n][k] = W[layer][k][n] ----
    int wb = bid - N_;
    int layer = wb / 576;
    int rem = wb % 576;
    int k0 = (rem % 24) * 32, n0 = (rem / 24) * 32;
    const float* Ws[3] = {W0, W1, W2};
    const float* W = Ws[layer];
    __hip_bfloat16* O = Wt + (size_t)layer * H_ * H_;
    __shared__ float tbuf[32][33];
    int x = threadIdx.x % 32, y = threadIdx.x / 32;
    for (int i = 0; i < 32; i += 8)
      tbuf[y + i][x] = W[(size_t)(k0 + y + i) * H_ + n0 + x];
    __syncthreads();
    for (int i = 0; i < 32; i += 8)
      O[(size_t)(n0 + y + i) * H_ + k0 + x] = __float2bfloat16(tbuf[x][y + i]);
    return;
  }
  if (bid < N_ + NB_WT + NB_ZERO) {
    // ---- zero: avgp | el[3] | er[3] | counts | tickets (258048 B) ----
    int zi = bid - N_ - NB_WT;
    zero_base[zi * 256 + threadIdx.x] = make_int4(0, 0, 0, 0);
    return;
  }
  // ---- qf partials: q = b*8+c, rows c*64..c*64+63, plain writes ----
  {
    int q = bid - N_ - NB_WT - NB_ZERO;    // 0..511
    int b = q >> 3, l0 = (q & 7) * 64;
    int tid = threadIdx.x;
    if (tid >= 192) return;
    __shared__ float qm[64];
    if (tid < 64) {
      int l = l0 + tid;
      qm[tid] = (is_head[b * L_ + l] != 2 && segment_ids[b * L_ + l] == 0 && masks[b * L_ + l] > 0) ? 1.0f : 0.0f;
    }
    __syncthreads();
    float4 a = make_float4(0.f, 0.f, 0.f, 0.f);
    for (int i = 0; i < 64; i++) {
      if (qm[i] != 0.f) {
        float4 v = ((const float4*)(features + ((size_t)b * L_ + l0 + i) * H_))[tid];
        a.x += v.x; a.y += v.y; a.z += v.z; a.w += v.w;
      }
    }
    ((float4*)(qpart + (size_t)q * H_))[tid] = a;
  }
}

// -- dispatch 2: CSR count, last block performs the scan --------------------
__global__ __launch_bounds__(256) void k_count_scan(const int* __restrict__ dst,
                                                    int* __restrict__ counts,
                                                    int* __restrict__ offs,
                                                    int* __restrict__ cursor,
                                                    int* __restrict__ tickets) {
  int i = blockIdx.x * 256 + threadIdx.x;
  if (i < NE_) atomicAdd(&counts[dst[i]], 1);
  __threadfence();
  __syncthreads();
  __shared__ int lastf;
  if (threadIdx.x == 0)
    lastf = (atomicAdd(&tickets[0], 1) == (int)gridDim.x - 1) ? 1 : 0;
  __syncthreads();
  if (!lastf) return;
  // 256-thread exclusive scan over counts[8192] (32 elems/thread)
  __shared__ int part[256];
  int base = threadIdx.x * 32;
  int c[32];
  int s = 0;
#pragma unroll
  for (int j = 0; j < 32; j++) {
    c[j] = __hip_atomic_load(&counts[base + j], __ATOMIC_RELAXED, __HIP_MEMORY_SCOPE_AGENT);
    s += c[j];
  }
  part[threadIdx.x] = s;
  __syncthreads();
  for (int off = 1; off < 256; off <<= 1) {
    int v = (threadIdx.x >= off) ? part[threadIdx.x - off] : 0;
    __syncthreads();
    part[threadIdx.x] += v;
    __syncthreads();
  }
  int run = threadIdx.x ? part[threadIdx.x - 1] : 0;
#pragma unroll
  for (int j = 0; j < 32; j++) {
    offs[base + j] = run;
    cursor[base + j] = run;
    run += c[j];
  }
  if (threadIdx.x == 255) offs[N_] = run;
}

__global__ void k_scatter(const int* __restrict__ dst, const int* __restrict__ src,
                          int* __restrict__ cursor, int* __restrict__ esrc, int ne) {
  int i = blockIdx.x * 256 + threadIdx.x;
  if (i < ne) { int p = atomicAdd(&cursor[dst[i]], 1); esrc[p] = src[i]; }
}

// ------ bf16 MFMA GEMM + fused el/er; z written as fp8 e4m3 ---------------
__global__ __launch_bounds__(256) void k_gemm_bf16(const __hip_bfloat16* __restrict__ A,
                                                   const __hip_bfloat16* __restrict__ Bt,
                                                   unsigned char* __restrict__ C,
                                                   const float* __restrict__ al,
                                                   const float* __restrict__ ar,
                                                   float* __restrict__ el,
                                                   float* __restrict__ er) {
  __shared__ __hip_bfloat16 As[2][128 * 32];
  __shared__ __hip_bfloat16 Bs[2][128 * 32];
  int tid = threadIdx.x;
  int bm = blockIdx.x * 128;
  int bn = blockIdx.y * 128;
  int w = tid >> 6;
  int l = tid & 63;
  int wr = w >> 1, wc = w & 1;
  int lr = l & 15;
  int lk = (l >> 4) * 8;
  f32x4 acc[4][4] = {};

  const __hip_bfloat16* gA[2];
  const __hip_bfloat16* gB[2];
  int ldsoff[2];
#pragma unroll
  for (int i = 0; i < 2; i++) {
    int idx = i * 256 + tid;
    int row = idx >> 2;
    int ck = (idx & 3) * 8;
    gA[i] = A + (size_t)(bm + row) * KDIM + ck;
    gB[i] = Bt + (size_t)(bn + row) * KDIM + ck;
    ldsoff[i] = idx * 8;
  }

  auto stage = [&](int buf, int k0) {
#pragma unroll
    for (int i = 0; i < 2; i++) GLOAD_LDS16(gA[i] + k0, &As[buf][ldsoff[i]]);
#pragma unroll
    for (int i = 0; i < 2; i++) GLOAD_LDS16(gB[i] + k0, &Bs[buf][ldsoff[i]]);
  };

  stage(0, 0);
  __syncthreads();

  constexpr int NT = KDIM / 32;
  for (int t = 0; t < NT; t++) {
    int cur = t & 1;
    if (t < NT - 1) stage(cur ^ 1, (t + 1) * 32);
    short8v a_frag[4], b_frag[4];
#pragma unroll
    for (int m = 0; m < 4; m++)
      a_frag[m] = *(const short8v*)&As[cur][(wr * 64 + m * 16 + lr) * 32 + lk];
#pragma unroll
    for (int n = 0; n < 4; n++)
      b_frag[n] = *(const short8v*)&Bs[cur][(wc * 64 + n * 16 + lr) * 32 + lk];
#pragma unroll
    for (int m = 0; m < 4; m++)
#pragma unroll
      for (int n = 0; n < 4; n++)
        acc[m][n] = __builtin_amdgcn_mfma_f32_16x16x32_bf16(a_frag[m], b_frag[n], acc[m][n], 0, 0, 0);
    __syncthreads();
  }

  float alv[4], arv[4];
#pragma unroll
  for (int n = 0; n < 4; n++) {
    int col = bn + wc * 64 + n * 16 + lr;
    alv[n] = al[col]; arv[n] = ar[col];
  }
  // C/D layout: col = lane&15, row = (lane>>4)*4 + r  [verified m89/m91]
#pragma unroll
  for (int m = 0; m < 4; m++) {
    int rbase = bm + wr * 64 + m * 16 + (l >> 4) * 4;
#pragma unroll
    for (int n = 0; n < 4; n++) {
      int col = bn + wc * 64 + n * 16 + lr;
#pragma unroll
      for (int r = 0; r < 4; r++) {
        float v = acc[m][n][r];
        int pk = __builtin_amdgcn_cvt_pk_fp8_f32(v, v, 0, false);
        C[(size_t)(rbase + r) * H_ + col] = (unsigned char)(pk & 0xff);
      }
    }
#pragma unroll
    for (int r = 0; r < 4; r++) {
      float pel = 0.f, per_ = 0.f;
#pragma unroll
      for (int n = 0; n < 4; n++) {
        pel  += acc[m][n][r] * alv[n];
        per_ += acc[m][n][r] * arv[n];
      }
#pragma unroll
      for (int off2 = 1; off2 < 16; off2 <<= 1) {
        pel  += __shfl_xor(pel,  off2);
        per_ += __shfl_xor(per_, off2);
      }
      if (lr == 0) {
        atomicAdd(&el[rbase + r], pel);
        atomicAdd(&er[rbase + r], per_);
      }
    }
  }
}

// ------- wave-per-dst-node softmax + agg (fp8 z), XCD-partition swizzle ----
__global__ __launch_bounds__(256) void k_agg(const unsigned char* __restrict__ z,
                                             const float* __restrict__ el,
                                             const float* __restrict__ er,
                                             const int* __restrict__ offs,
                                             const int* __restrict__ esrc,
                                             __hip_bfloat16* __restrict__ hout) {
  // partition p (1024 nodes) -> XCD p: all z gathers stay in one L2 (786 KB)
  int nb = ((blockIdx.x & 7) << 8) + (blockIdx.x >> 3);   // grid 2048 = 8*256
  int wv = threadIdx.x >> 6, lane = threadIdx.x & 63;
  int n = nb * 4 + wv;
  int o0 = offs[n];
  int deg = offs[n + 1] - o0;
  float ern = er[n];
  float acc[12] = {};

  if (deg <= 64) {
    float w_ = 0.f; int s_ = 0;
    if (lane < deg) {
      s_ = esrc[o0 + lane];
      float v = el[s_] + ern;
      w_ = v > 0.f ? v : NEG_SLOPE * v;
    } else {
      w_ = -1e30f;
    }
    float m = w_;
    for (int off = 32; off; off >>= 1) m = fmaxf(m, __shfl_xor(m, off));
    float ex = (lane < deg) ? __expf(w_ - m) : 0.f;
    float sum = ex;
    for (int off = 32; off; off >>= 1) sum += __shfl_xor(sum, off);
    w_ = ex / sum;
    for (int j = 0; j < deg; j++) {
      float wj = __shfl(w_, j);
      int sj = __shfl(s_, j);
      const unsigned* zr = (const unsigned*)(z + (size_t)sj * H_);
#pragma unroll
      for (int i = 0; i < 3; i++) {
        unsigned u = zr[lane + i * 64];
        acc[i * 4 + 0] += wj * __builtin_amdgcn_cvt_f32_fp8(u, 0);
        acc[i * 4 + 1] += wj * __builtin_amdgcn_cvt_f32_fp8(u, 1);
        acc[i * 4 + 2] += wj * __builtin_amdgcn_cvt_f32_fp8(u, 2);
        acc[i * 4 + 3] += wj * __builtin_amdgcn_cvt_f32_fp8(u, 3);
      }
    }
  } else {
    float lmax = -1e30f;
    for (int i = lane; i < deg; i += 64) {
      float v = el[esrc[o0 + i]] + ern;
      v = v > 0.f ? v : NEG_SLOPE * v;
      lmax = fmaxf(lmax, v);
    }
    for (int off = 32; off; off >>= 1) lmax = fmaxf(lmax, __shfl_xor(lmax, off));
    float lsum = 0.f;
    for (int i = lane; i < deg; i += 64) {
      float v = el[esrc[o0 + i]] + ern;
      v = v > 0.f ? v : NEG_SLOPE * v;
      lsum += __expf(v - lmax);
    }
    for (int off = 32; off; off >>= 1) lsum += __shfl_xor(lsum, off);
    float inv = 1.0f / lsum;
    for (int base = 0; base < deg; base += 64) {
      int chunk = min(64, deg - base);
      float w_ = 0.f; int s_ = 0;
      if (lane < chunk) {
        s_ = esrc[o0 + base + lane];
        float v = el[s_] + ern;
        v = v > 0.f ? v : NEG_SLOPE * v;
        w_ = __expf(v - lmax) * inv;
      }
      for (int j = 0; j < chunk; j++) {
        float wj = __shfl(w_, j);
        int sj = __shfl(s_, j);
        const unsigned* zr = (const unsigned*)(z + (size_t)sj * H_);
#pragma unroll
        for (int i = 0; i < 3; i++) {
          unsigned u = zr[lane + i * 64];
          acc[i * 4 + 0] += wj * __builtin_amdgcn_cvt_f32_fp8(u, 0);
          acc[i * 4 + 1] += wj * __builtin_amdgcn_cvt_f32_fp8(u, 1);
          acc[i * 4 + 2] += wj * __builtin_amdgcn_cvt_f32_fp8(u, 2);
          acc[i * 4 + 3] += wj * __builtin_amdgcn_cvt_f32_fp8(u, 3);
        }
      }
    }
  }

  short4* ho = (short4*)(hout + (size_t)n * H_);
#pragma unroll
  for (int i = 0; i < 3; i++) {
    float e0 = acc[i * 4 + 0]; e0 = e0 > 0.f ? e0 : __expf(e0) - 1.f;
    float e1 = acc[i * 4 + 1]; e1 = e1 > 0.f ? e1 : __expf(e1) - 1.f;
    float e2 = acc[i * 4 + 2]; e2 = e2 > 0.f ? e2 : __expf(e2) - 1.f;
    float e3 = acc[i * 4 + 3]; e3 = e3 > 0.f ? e3 : __expf(e3) - 1.f;
    short4 o; o.x = f2bf(e0); o.y = f2bf(e1); o.z = f2bf(e2); o.w = f2bf(e3);
    ho[lane + i * 64] = o;
  }
}

// -- dispatch 10: per-doc node mean (atomics); last block computes out ------
__global__ __launch_bounds__(192) void k_avg_final(const __hip_bfloat16* __restrict__ h,
                                                   const int* __restrict__ doc_spans,
                                                   float* __restrict__ avgp,
                                                   const float* __restrict__ qpart,
                                                   float* __restrict__ out,
                                                   int* __restrict__ tickets) {
  int b = blockIdx.x >> 3;
  int s0 = (blockIdx.x & 7) * 16;
  int tid = threadIdx.x;
  {
    float4 a = make_float4(0.f, 0.f, 0.f, 0.f);
    for (int i = 0; i < 16; i++) {
      short4 v = ((const short4*)(h + ((size_t)(b * S_ + s0 + i)) * H_))[tid];
      a.x += bf2f(v.x); a.y += bf2f(v.y); a.z += bf2f(v.z); a.w += bf2f(v.w);
    }
    int d = docof(b, doc_spans);
    atomicAdd(&avgp[d * H_ + tid * 4 + 0], a.x);
    atomicAdd(&avgp[d * H_ + tid * 4 + 1], a.y);
    atomicAdd(&avgp[d * H_ + tid * 4 + 2], a.z);
    atomicAdd(&avgp[d * H_ + tid * 4 + 3], a.w);
  }
  __threadfence();
  __syncthreads();
  __shared__ int lastf;
  if (tid == 0)
    lastf = (atomicAdd(&tickets[1], 1) == (int)gridDim.x - 1) ? 1 : 0;
  __syncthreads();
  if (!lastf) return;

  // final: 3 waves cover 8 docs
  int lane = tid & 63;
  for (int d = tid >> 6; d < D_; d += 3) {
    int nsent = 0;
    for (int bb = 0; bb < B_; bb++)
      nsent += (docof(bb, doc_spans) == d) ? 1 : 0;
    float inv_node = 1.0f / fmaxf((float)nsent * (float)S_, 1.0f);
    float inv_doc  = 1.0f / fmaxf((float)(doc_spans[d * 2 + 1] - doc_spans[d * 2]), 1.0f);
    float acc = 0.f;
    for (int hh = lane; hh < H_; hh += 64) {
      float qa = 0.f;
      for (int bb = 0; bb < B_; bb++) {
        if (docof(bb, doc_spans) == d) {
          const float* qp = qpart + (size_t)bb * 8 * H_ + hh;
#pragma unroll
          for (int c = 0; c < 8; c++) qa += qp[(size_t)c * H_];
        }
      }
      float av = aload(&avgp[d * H_ + hh]);
      acc += fabsf(qa * inv_doc - av * inv_node);
    }
    for (int off = 32; off; off >>= 1) acc += __shfl_xor(acc, off);
    if (lane == 0) out[d] = acc;
  }
}

extern "C" void kernel_launch(void* const* d_in, const int* in_sizes, int n_in,
                              void* d_out, int out_size, void* d_ws, size_t ws_size,
                              hipStream_t stream) {
  const float* features     = (const float*)d_in[0];
  const int*   token_spans  = (const int*)d_in[1];
  const int*   masks        = (const int*)d_in[2];
  const int*   selidx       = (const int*)d_in[3];
  const int*   src          = (const int*)d_in[4];
  const int*   dst          = (const int*)d_in[5];
  const int*   doc_spans    = (const int*)d_in[6];
  const int*   segment_ids  = (const int*)d_in[7];
  const int*   is_head      = (const int*)d_in[8];
  const float* Wl[3]  = {(const float*)d_in[9],  (const float*)d_in[12], (const float*)d_in[15]};
  const float* alv[3] = {(const float*)d_in[10], (const float*)d_in[13], (const float*)d_in[16]};
  const float* arv[3] = {(const float*)d_in[11], (const float*)d_in[14], (const float*)d_in[17]};
  float* out = (float*)d_out;

  char* ws = (char*)d_ws;
  size_t off = 0;
  auto alloc = [&](size_t bytes) -> void* {
    void* p = ws + off;
    off = (off + bytes + 255) & ~(size_t)255;
    return p;
  };
  __hip_bfloat16* hA = (__hip_bfloat16*)alloc((size_t)N_ * H_ * 2);   // bf16 h
  unsigned char*  hB = (unsigned char*)alloc((size_t)N_ * H_);        // fp8 z
  __hip_bfloat16* Wt = (__hip_bfloat16*)alloc((size_t)3 * H_ * H_ * 2);
  // ---- contiguous zero region: avgp | el[3] | er[3] | counts | tickets ----
  // 24576 + 98304 + 98304 + 32768 + 4096 = 258048 B = 63 blocks * 4096 B
  float* avgp    = (float*)alloc((size_t)D_ * H_ * 4);
  float* el      = (float*)alloc((size_t)3 * N_ * 4);
  float* er      = (float*)alloc((size_t)3 * N_ * 4);
  int*   counts  = (int*)alloc((size_t)N_ * 4);
  int*   tickets = (int*)alloc((size_t)4096);
  // ---- rest of scratch ----
  float* qpart  = (float*)alloc((size_t)NB_QF * H_ * 4);   // per-(b,chunk) qf partials
  int*   offs   = (int*)alloc((size_t)(N_ + 1) * 4);
  int*   cursor = (int*)alloc((size_t)N_ * 4);
  int*   esrc   = (int*)alloc((size_t)NE_ * 4);

  // dispatch 1: token pooling + W transposes + zero-fill + qf partials
  k_prep<<<N_ + NB_WT + NB_ZERO + NB_QF, 256, 0, stream>>>(
      features, token_spans, masks, selidx, hA, Wl[0], Wl[1], Wl[2], Wt,
      (int4*)avgp, segment_ids, is_head, qpart);

  // dispatch 2+3: CSR build (count + folded scan, then scatter)
  k_count_scan<<<(NE_ + 255) / 256, 256, 0, stream>>>(dst, counts, offs, cursor, tickets);
  k_scatter<<<(NE_ + 255) / 256, 256, 0, stream>>>(dst, src, cursor, esrc, NE_);

  // dispatches 4-9: 3 GAT layers
  for (int i = 0; i < 3; i++) {
    k_gemm_bf16<<<dim3(N_ / 128, H_ / 128), 256, 0, stream>>>(
        hA, Wt + (size_t)i * H_ * H_, hB, alv[i], arv[i],
        el + (size_t)i * N_, er + (size_t)i * N_);
    k_agg<<<N_ / 4, 256, 0, stream>>>(hB, el + (size_t)i * N_, er + (size_t)i * N_,
                                      offs, esrc, hA);
  }

  // dispatch 10: avg atomics + folded final
  k_avg_final<<<B_ * 8, 192, 0, stream>>>(hA, doc_spans, avgp, qpart, out, tickets);
}

// Round 12
// 250.375 us; speedup vs baseline: 2.2297x; 2.2297x over previous
//
#include <hip/hip_runtime.h>
#include <hip/hip_bf16.h>

// Problem constants (fixed by setup_inputs)
constexpr int B_ = 64, L_ = 512, H_ = 768, T_ = 256, S_ = 128, D_ = 8;
constexpr int N_ = B_ * S_;        // 8192 nodes
constexpr int E0_ = 16 * N_;       // 131072 random edges
constexpr int NE_ = E0_ + N_;      // + self loops = 139264
constexpr float NEG_SLOPE = 0.2f;
constexpr int KDIM = 768;          // GEMM K (= H_)
constexpr int NB_WT = 3 * 576;     // W-transpose blocks
constexpr int NB_ZERO = 63;        // zero-fill blocks (63*4096 B = 258048 B)
constexpr int NB_QF = 512;         // qf partial blocks (b*8+chunk)

typedef __attribute__((ext_vector_type(8))) short short8v;
typedef __attribute__((ext_vector_type(4))) float f32x4;

#define GLOAD_LDS16(g, l) __builtin_amdgcn_global_load_lds( \
    (const __attribute__((address_space(1))) void*)(g), \
    (__attribute__((address_space(3))) void*)(l), 16, 0, 0)

__device__ __forceinline__ float bf2f(short s) {
  unsigned u = ((unsigned)(unsigned short)s) << 16;
  return __builtin_bit_cast(float, u);
}
__device__ __forceinline__ short f2bf(float f) {
  return (short)__bfloat16_as_ushort(__float2bfloat16(f));
}
__device__ __forceinline__ int docof(int b, const int* __restrict__ doc_spans) {
  int cnt = 0;
  for (int dd = 0; dd < D_; dd++) cnt += (doc_spans[dd * 2] <= b) ? 1 : 0;
  return cnt - 1;
}

// -- dispatch 1: token pooling | W transpose | zero-fill | qf partials ------
__global__ __launch_bounds__(256) void k_prep(const float* __restrict__ features,
                                              const int* __restrict__ token_spans,
                                              const int* __restrict__ masks,
                                              const int* __restrict__ selidx,
                                              __hip_bfloat16* __restrict__ h0,
                                              const float* __restrict__ W0,
                                              const float* __restrict__ W1,
                                              const float* __restrict__ W2,
                                              __hip_bfloat16* __restrict__ Wt,
                                              int4* __restrict__ zero_base,
                                              const int* __restrict__ segment_ids,
                                              const int* __restrict__ is_head,
                                              float* __restrict__ qpart) {
  int bid = blockIdx.x;
  if (bid < N_) {
    // ---- token pooling: one block per node, 192 active lanes ----
    if (threadIdx.x >= 192) return;
    int n = bid;
    int b = n / S_;
    int t = selidx[n];
    int st = token_spans[(b * T_ + t) * 2 + 0];
    int en = token_spans[(b * T_ + t) * 2 + 1];
    int tid = threadIdx.x;
    float4 a = make_float4(0.f, 0.f, 0.f, 0.f);
    int cnt = 0;
    for (int l = st; l < en; l++) {
      if (masks[b * L_ + l] > 0) {
        cnt++;
        float4 v = ((const float4*)(features + ((size_t)b * L_ + l) * H_))[tid];
        a.x += v.x; a.y += v.y; a.z += v.z; a.w += v.w;
      }
    }
    float sc = (en > 0) ? (1.0f / (float)max(cnt, 1)) : 0.0f;
    short4 o;
    o.x = f2bf(a.x * sc); o.y = f2bf(a.y * sc); o.z = f2bf(a.z * sc); o.w = f2bf(a.w * sc);
    ((short4*)(h0 + (size_t)n * H_))[tid] = o;
    return;
  }
  if (bid < N_ + NB_WT) {
    // ---- W transpose + bf16: Wt[layer][n][k] = W[layer][k][n] ----
    int wb = bid - N_;
    int layer = wb / 576;
    int rem = wb % 576;
    int k0 = (rem % 24) * 32, n0 = (rem / 24) * 32;
    const float* Ws[3] = {W0, W1, W2};
    const float* W = Ws[layer];
    __hip_bfloat16* O = Wt + (size_t)layer * H_ * H_;
    __shared__ float tbuf[32][33];
    int x = threadIdx.x % 32, y = threadIdx.x / 32;
    for (int i = 0; i < 32; i += 8)
      tbuf[y + i][x] = W[(size_t)(k0 + y + i) * H_ + n0 + x];
    __syncthreads();
    for (int i = 0; i < 32; i += 8)
      O[(size_t)(n0 + y + i) * H_ + k0 + x] = __float2bfloat16(tbuf[x][y + i]);
    return;
  }
  if (bid < N_ + NB_WT + NB_ZERO) {
    // ---- zero: avgp | el[3] | er[3] | counts | tickets (258048 B) ----
    int zi = bid - N_ - NB_WT;
    zero_base[zi * 256 + threadIdx.x] = make_int4(0, 0, 0, 0);
    return;
  }
  // ---- qf partials: q = b*8+c, rows c*64..c*64+63, plain writes ----
  {
    int q = bid - N_ - NB_WT - NB_ZERO;    // 0..511
    int b = q >> 3, l0 = (q & 7) * 64;
    int tid = threadIdx.x;
    if (tid >= 192) return;
    __shared__ float qm[64];
    if (tid < 64) {
      int l = l0 + tid;
      qm[tid] = (is_head[b * L_ + l] != 2 && segment_ids[b * L_ + l] == 0 && masks[b * L_ + l] > 0) ? 1.0f : 0.0f;
    }
    __syncthreads();
    float4 a = make_float4(0.f, 0.f, 0.f, 0.f);
    for (int i = 0; i < 64; i++) {
      if (qm[i] != 0.f) {
        float4 v = ((const float4*)(features + ((size_t)b * L_ + l0 + i) * H_))[tid];
        a.x += v.x; a.y += v.y; a.z += v.z; a.w += v.w;
      }
    }
    ((float4*)(qpart + (size_t)q * H_))[tid] = a;
  }
}

// -- dispatch 2: CSR count, last block performs the scan --------------------
__global__ __launch_bounds__(256) void k_count_scan(const int* __restrict__ dst,
                                                    int* __restrict__ counts,
                                                    int* __restrict__ offs,
                                                    int* __restrict__ cursor,
                                                    int* __restrict__ tickets) {
  int i = blockIdx.x * 256 + threadIdx.x;
  if (i < NE_) atomicAdd(&counts[dst[i]], 1);
  __threadfence();
  __syncthreads();
  __shared__ int lastf;
  if (threadIdx.x == 0)
    lastf = (atomicAdd(&tickets[0], 1) == (int)gridDim.x - 1) ? 1 : 0;
  __syncthreads();
  if (!lastf) return;
  // 256-thread exclusive scan over counts[8192] (32 elems/thread)
  __shared__ int part[256];
  int base = threadIdx.x * 32;
  int c[32];
  int s = 0;
#pragma unroll
  for (int j = 0; j < 32; j++) {
    c[j] = __hip_atomic_load(&counts[base + j], __ATOMIC_RELAXED, __HIP_MEMORY_SCOPE_AGENT);
    s += c[j];
  }
  part[threadIdx.x] = s;
  __syncthreads();
  for (int off = 1; off < 256; off <<= 1) {
    int v = (threadIdx.x >= off) ? part[threadIdx.x - off] : 0;
    __syncthreads();
    part[threadIdx.x] += v;
    __syncthreads();
  }
  int run = threadIdx.x ? part[threadIdx.x - 1] : 0;
#pragma unroll
  for (int j = 0; j < 32; j++) {
    offs[base + j] = run;
    cursor[base + j] = run;
    run += c[j];
  }
  if (threadIdx.x == 255) offs[N_] = run;
}

__global__ void k_scatter(const int* __restrict__ dst, const int* __restrict__ src,
                          int* __restrict__ cursor, int* __restrict__ esrc, int ne) {
  int i = blockIdx.x * 256 + threadIdx.x;
  if (i < ne) { int p = atomicAdd(&cursor[dst[i]], 1); esrc[p] = src[i]; }
}

// ------ bf16 MFMA GEMM + fused el/er; z written as fp8 e4m3 ---------------
__global__ __launch_bounds__(256) void k_gemm_bf16(const __hip_bfloat16* __restrict__ A,
                                                   const __hip_bfloat16* __restrict__ Bt,
                                                   unsigned char* __restrict__ C,
                                                   const float* __restrict__ al,
                                                   const float* __restrict__ ar,
                                                   float* __restrict__ el,
                                                   float* __restrict__ er) {
  __shared__ __hip_bfloat16 As[2][128 * 32];
  __shared__ __hip_bfloat16 Bs[2][128 * 32];
  int tid = threadIdx.x;
  int bm = blockIdx.x * 128;
  int bn = blockIdx.y * 128;
  int w = tid >> 6;
  int l = tid & 63;
  int wr = w >> 1, wc = w & 1;
  int lr = l & 15;
  int lk = (l >> 4) * 8;
  f32x4 acc[4][4] = {};

  const __hip_bfloat16* gA[2];
  const __hip_bfloat16* gB[2];
  int ldsoff[2];
#pragma unroll
  for (int i = 0; i < 2; i++) {
    int idx = i * 256 + tid;
    int row = idx >> 2;
    int ck = (idx & 3) * 8;
    gA[i] = A + (size_t)(bm + row) * KDIM + ck;
    gB[i] = Bt + (size_t)(bn + row) * KDIM + ck;
    ldsoff[i] = idx * 8;
  }

  auto stage = [&](int buf, int k0) {
#pragma unroll
    for (int i = 0; i < 2; i++) GLOAD_LDS16(gA[i] + k0, &As[buf][ldsoff[i]]);
#pragma unroll
    for (int i = 0; i < 2; i++) GLOAD_LDS16(gB[i] + k0, &Bs[buf][ldsoff[i]]);
  };

  stage(0, 0);
  __syncthreads();

  constexpr int NT = KDIM / 32;
  for (int t = 0; t < NT; t++) {
    int cur = t & 1;
    if (t < NT - 1) stage(cur ^ 1, (t + 1) * 32);
    short8v a_frag[4], b_frag[4];
#pragma unroll
    for (int m = 0; m < 4; m++)
      a_frag[m] = *(const short8v*)&As[cur][(wr * 64 + m * 16 + lr) * 32 + lk];
#pragma unroll
    for (int n = 0; n < 4; n++)
      b_frag[n] = *(const short8v*)&Bs[cur][(wc * 64 + n * 16 + lr) * 32 + lk];
#pragma unroll
    for (int m = 0; m < 4; m++)
#pragma unroll
      for (int n = 0; n < 4; n++)
        acc[m][n] = __builtin_amdgcn_mfma_f32_16x16x32_bf16(a_frag[m], b_frag[n], acc[m][n], 0, 0, 0);
    __syncthreads();
  }

  float alv[4], arv[4];
#pragma unroll
  for (int n = 0; n < 4; n++) {
    int col = bn + wc * 64 + n * 16 + lr;
    alv[n] = al[col]; arv[n] = ar[col];
  }
  // C/D layout: col = lane&15, row = (lane>>4)*4 + r  [verified m89/m91]
#pragma unroll
  for (int m = 0; m < 4; m++) {
    int rbase = bm + wr * 64 + m * 16 + (l >> 4) * 4;
#pragma unroll
    for (int n = 0; n < 4; n++) {
      int col = bn + wc * 64 + n * 16 + lr;
#pragma unroll
      for (int r = 0; r < 4; r++) {
        float v = acc[m][n][r];
        int pk = __builtin_amdgcn_cvt_pk_fp8_f32(v, v, 0, false);
        C[(size_t)(rbase + r) * H_ + col] = (unsigned char)(pk & 0xff);
      }
    }
#pragma unroll
    for (int r = 0; r < 4; r++) {
      float pel = 0.f, per_ = 0.f;
#pragma unroll
      for (int n = 0; n < 4; n++) {
        pel  += acc[m][n][r] * alv[n];
        per_ += acc[m][n][r] * arv[n];
      }
#pragma unroll
      for (int off2 = 1; off2 < 16; off2 <<= 1) {
        pel  += __shfl_xor(pel,  off2);
        per_ += __shfl_xor(per_, off2);
      }
      if (lr == 0) {
        atomicAdd(&el[rbase + r], pel);
        atomicAdd(&er[rbase + r], per_);
      }
    }
  }
}

// ------- wave-per-dst-node softmax + agg (fp8 z), XCD-partition swizzle ----
__global__ __launch_bounds__(256) void k_agg(const unsigned char* __restrict__ z,
                                             const float* __restrict__ el,
                                             const float* __restrict__ er,
                                             const int* __restrict__ offs,
                                             const int* __restrict__ esrc,
                                             __hip_bfloat16* __restrict__ hout) {
  // partition p (1024 nodes) -> XCD p: all z gathers stay in one L2 (786 KB)
  int nb = ((blockIdx.x & 7) << 8) + (blockIdx.x >> 3);   // grid 2048 = 8*256
  int wv = threadIdx.x >> 6, lane = threadIdx.x & 63;
  int n = nb * 4 + wv;
  int o0 = offs[n];
  int deg = offs[n + 1] - o0;
  float ern = er[n];
  float acc[12] = {};

  if (deg <= 64) {
    float w_ = 0.f; int s_ = 0;
    if (lane < deg) {
      s_ = esrc[o0 + lane];
      float v = el[s_] + ern;
      w_ = v > 0.f ? v : NEG_SLOPE * v;
    } else {
      w_ = -1e30f;
    }
    float m = w_;
    for (int off = 32; off; off >>= 1) m = fmaxf(m, __shfl_xor(m, off));
    float ex = (lane < deg) ? __expf(w_ - m) : 0.f;
    float sum = ex;
    for (int off = 32; off; off >>= 1) sum += __shfl_xor(sum, off);
    w_ = ex / sum;
    for (int j = 0; j < deg; j++) {
      float wj = __shfl(w_, j);
      int sj = __shfl(s_, j);
      const unsigned* zr = (const unsigned*)(z + (size_t)sj * H_);
#pragma unroll
      for (int i = 0; i < 3; i++) {
        unsigned u = zr[lane + i * 64];
        acc[i * 4 + 0] += wj * __builtin_amdgcn_cvt_f32_fp8(u, 0);
        acc[i * 4 + 1] += wj * __builtin_amdgcn_cvt_f32_fp8(u, 1);
        acc[i * 4 + 2] += wj * __builtin_amdgcn_cvt_f32_fp8(u, 2);
        acc[i * 4 + 3] += wj * __builtin_amdgcn_cvt_f32_fp8(u, 3);
      }
    }
  } else {
    float lmax = -1e30f;
    for (int i = lane; i < deg; i += 64) {
      float v = el[esrc[o0 + i]] + ern;
      v = v > 0.f ? v : NEG_SLOPE * v;
      lmax = fmaxf(lmax, v);
    }
    for (int off = 32; off; off >>= 1) lmax = fmaxf(lmax, __shfl_xor(lmax, off));
    float lsum = 0.f;
    for (int i = lane; i < deg; i += 64) {
      float v = el[esrc[o0 + i]] + ern;
      v = v > 0.f ? v : NEG_SLOPE * v;
      lsum += __expf(v - lmax);
    }
    for (int off = 32; off; off >>= 1) lsum += __shfl_xor(lsum, off);
    float inv = 1.0f / lsum;
    for (int base = 0; base < deg; base += 64) {
      int chunk = min(64, deg - base);
      float w_ = 0.f; int s_ = 0;
      if (lane < chunk) {
        s_ = esrc[o0 + base + lane];
        float v = el[s_] + ern;
        v = v > 0.f ? v : NEG_SLOPE * v;
        w_ = __expf(v - lmax) * inv;
      }
      for (int j = 0; j < chunk; j++) {
        float wj = __shfl(w_, j);
        int sj = __shfl(s_, j);
        const unsigned* zr = (const unsigned*)(z + (size_t)sj * H_);
#pragma unroll
        for (int i = 0; i < 3; i++) {
          unsigned u = zr[lane + i * 64];
          acc[i * 4 + 0] += wj * __builtin_amdgcn_cvt_f32_fp8(u, 0);
          acc[i * 4 + 1] += wj * __builtin_amdgcn_cvt_f32_fp8(u, 1);
          acc[i * 4 + 2] += wj * __builtin_amdgcn_cvt_f32_fp8(u, 2);
          acc[i * 4 + 3] += wj * __builtin_amdgcn_cvt_f32_fp8(u, 3);
        }
      }
    }
  }

  short4* ho = (short4*)(hout + (size_t)n * H_);
#pragma unroll
  for (int i = 0; i < 3; i++) {
    float e0 = acc[i * 4 + 0]; e0 = e0 > 0.f ? e0 : __expf(e0) - 1.f;
    float e1 = acc[i * 4 + 1]; e1 = e1 > 0.f ? e1 : __expf(e1) - 1.f;
    float e2 = acc[i * 4 + 2]; e2 = e2 > 0.f ? e2 : __expf(e2) - 1.f;
    float e3 = acc[i * 4 + 3]; e3 = e3 > 0.f ? e3 : __expf(e3) - 1.f;
    short4 o; o.x = f2bf(e0); o.y = f2bf(e1); o.z = f2bf(e2); o.w = f2bf(e3);
    ho[lane + i * 64] = o;
  }
}

// -- per-doc node mean: grid (B*8), atomics into avgp ----------------------
__global__ __launch_bounds__(192) void k_avg(const __hip_bfloat16* __restrict__ h,
                                             const int* __restrict__ doc_spans,
                                             float* __restrict__ avgp) {
  int b = blockIdx.x >> 3;
  int s0 = (blockIdx.x & 7) * 16;
  int tid = threadIdx.x;
  float4 a = make_float4(0.f, 0.f, 0.f, 0.f);
  for (int i = 0; i < 16; i++) {
    short4 v = ((const short4*)(h + ((size_t)(b * S_ + s0 + i)) * H_))[tid];
    a.x += bf2f(v.x); a.y += bf2f(v.y); a.z += bf2f(v.z); a.w += bf2f(v.w);
  }
  int d = docof(b, doc_spans);
  atomicAdd(&avgp[d * H_ + tid * 4 + 0], a.x);
  atomicAdd(&avgp[d * H_ + tid * 4 + 1], a.y);
  atomicAdd(&avgp[d * H_ + tid * 4 + 2], a.z);
  atomicAdd(&avgp[d * H_ + tid * 4 + 3], a.w);
}

// -- qfsum: qfp[d][h] = sum over b in doc d, chunks c of qpart -------------
// grid (D_, 6), 128 threads; doc_spans in LDS; coalesced across threads
__global__ __launch_bounds__(128) void k_qfsum(const float* __restrict__ qpart,
                                               const int* __restrict__ doc_spans,
                                               float* __restrict__ qfp) {
  __shared__ int ds[D_ * 2];
  int tid = threadIdx.x;
  if (tid < D_ * 2) ds[tid] = doc_spans[tid];
  __syncthreads();
  int d = blockIdx.x;
  int hh = blockIdx.y * 128 + tid;
  float acc = 0.f;
  for (int b = 0; b < B_; b++) {
    int cnt = 0;
#pragma unroll
    for (int dd = 0; dd < D_; dd++) cnt += (ds[dd * 2] <= b) ? 1 : 0;
    if (cnt - 1 != d) continue;
    const float* qp = qpart + (size_t)b * 8 * H_ + hh;
#pragma unroll
    for (int c = 0; c < 8; c++) acc += qp[(size_t)c * H_];
  }
  qfp[d * H_ + hh] = acc;
}

// ---------------- final: out[d] = sum_h |qf/doccnt - avg/nodecnt| ----------
__global__ __launch_bounds__(512) void k_final(const float* __restrict__ qfp,
                                               const float* __restrict__ avgp,
                                               const int* __restrict__ doc_spans,
                                               float* __restrict__ out) {
  __shared__ int ds[D_ * 2];
  int tid = threadIdx.x;
  if (tid < D_ * 2) ds[tid] = doc_spans[tid];
  __syncthreads();
  int d = tid >> 6, lane = tid & 63;
  int nsent = 0;
  for (int b = 0; b < B_; b++) {
    int cnt = 0;
#pragma unroll
    for (int dd = 0; dd < D_; dd++) cnt += (ds[dd * 2] <= b) ? 1 : 0;
    nsent += ((cnt - 1) == d) ? 1 : 0;
  }
  float inv_node = 1.0f / fmaxf((float)nsent * (float)S_, 1.0f);
  float inv_doc  = 1.0f / fmaxf((float)(ds[d * 2 + 1] - ds[d * 2]), 1.0f);
  float acc = 0.f;
  for (int h = lane; h < H_; h += 64)
    acc += fabsf(qfp[d * H_ + h] * inv_doc - avgp[d * H_ + h] * inv_node);
  for (int off = 32; off; off >>= 1) acc += __shfl_xor(acc, off);
  if (lane == 0) out[d] = acc;
}

extern "C" void kernel_launch(void* const* d_in, const int* in_sizes, int n_in,
                              void* d_out, int out_size, void* d_ws, size_t ws_size,
                              hipStream_t stream) {
  const float* features     = (const float*)d_in[0];
  const int*   token_spans  = (const int*)d_in[1];
  const int*   masks        = (const int*)d_in[2];
  const int*   selidx       = (const int*)d_in[3];
  const int*   src          = (const int*)d_in[4];
  const int*   dst          = (const int*)d_in[5];
  const int*   doc_spans    = (const int*)d_in[6];
  const int*   segment_ids  = (const int*)d_in[7];
  const int*   is_head      = (const int*)d_in[8];
  const float* Wl[3]  = {(const float*)d_in[9],  (const float*)d_in[12], (const float*)d_in[15]};
  const float* alv[3] = {(const float*)d_in[10], (const float*)d_in[13], (const float*)d_in[16]};
  const float* arv[3] = {(const float*)d_in[11], (const float*)d_in[14], (const float*)d_in[17]};
  float* out = (float*)d_out;

  char* ws = (char*)d_ws;
  size_t off = 0;
  auto alloc = [&](size_t bytes) -> void* {
    void* p = ws + off;
    off = (off + bytes + 255) & ~(size_t)255;
    return p;
  };
  __hip_bfloat16* hA = (__hip_bfloat16*)alloc((size_t)N_ * H_ * 2);   // bf16 h
  unsigned char*  hB = (unsigned char*)alloc((size_t)N_ * H_);        // fp8 z
  __hip_bfloat16* Wt = (__hip_bfloat16*)alloc((size_t)3 * H_ * H_ * 2);
  // ---- contiguous zero region: avgp | el[3] | er[3] | counts | tickets ----
  // 24576 + 98304 + 98304 + 32768 + 4096 = 258048 B = 63 blocks * 4096 B
  float* avgp    = (float*)alloc((size_t)D_ * H_ * 4);
  float* el      = (float*)alloc((size_t)3 * N_ * 4);
  float* er      = (float*)alloc((size_t)3 * N_ * 4);
  int*   counts  = (int*)alloc((size_t)N_ * 4);
  int*   tickets = (int*)alloc((size_t)4096);
  // ---- rest of scratch ----
  float* qpart  = (float*)alloc((size_t)NB_QF * H_ * 4);   // per-(b,chunk) qf partials
  float* qfp    = (float*)alloc((size_t)D_ * H_ * 4);
  int*   offs   = (int*)alloc((size_t)(N_ + 1) * 4);
  int*   cursor = (int*)alloc((size_t)N_ * 4);
  int*   esrc   = (int*)alloc((size_t)NE_ * 4);

  // dispatch 1: token pooling + W transposes + zero-fill + qf partials
  k_prep<<<N_ + NB_WT + NB_ZERO + NB_QF, 256, 0, stream>>>(
      features, token_spans, masks, selidx, hA, Wl[0], Wl[1], Wl[2], Wt,
      (int4*)avgp, segment_ids, is_head, qpart);

  // dispatch 2+3: CSR build (count + folded scan, then scatter)
  k_count_scan<<<(NE_ + 255) / 256, 256, 0, stream>>>(dst, counts, offs, cursor, tickets);
  k_scatter<<<(NE_ + 255) / 256, 256, 0, stream>>>(dst, src, cursor, esrc, NE_);

  // dispatches 4-9: 3 GAT layers
  for (int i = 0; i < 3; i++) {
    k_gemm_bf16<<<dim3(N_ / 128, H_ / 128), 256, 0, stream>>>(
        hA, Wt + (size_t)i * H_ * H_, hB, alv[i], arv[i],
        el + (size_t)i * N_, er + (size_t)i * N_);
    k_agg<<<N_ / 4, 256, 0, stream>>>(hB, el + (size_t)i * N_, er + (size_t)i * N_,
                                      offs, esrc, hA);
  }

  // dispatches 10-12: doc reductions + final
  k_avg<<<B_ * 8, 192, 0, stream>>>(hA, doc_spans, avgp);
  k_qfsum<<<dim3(D_, 6), 128, 0, stream>>>(qpart, doc_spans, qfp);
  k_final<<<1, 512, 0, stream>>>(qfp, avgp, doc_spans, out);
}

// Round 13
// 210.171 us; speedup vs baseline: 2.6562x; 1.1913x over previous
//
#include <hip/hip_runtime.h>
#include <hip/hip_bf16.h>

// Problem constants (fixed by setup_inputs)
constexpr int B_ = 64, L_ = 512, H_ = 768, T_ = 256, S_ = 128, D_ = 8;
constexpr int N_ = B_ * S_;        // 8192 nodes
constexpr int E0_ = 16 * N_;       // 131072 random edges
constexpr int NE_ = E0_ + N_;      // + self loops = 139264
constexpr float NEG_SLOPE = 0.2f;
constexpr int KDIM = 768;          // GEMM K (= H_)
constexpr int NB_WT = 3 * 576;     // W-transpose blocks
constexpr int NB_ZERO = 68;        // zero-fill blocks (68*256 int4 = 272 KB)

typedef __attribute__((ext_vector_type(8))) short short8v;
typedef __attribute__((ext_vector_type(4))) float f32x4;

#define GLOAD_LDS16(g, l) __builtin_amdgcn_global_load_lds( \
    (const __attribute__((address_space(1))) void*)(g), \
    (__attribute__((address_space(3))) void*)(l), 16, 0, 0)

__device__ __forceinline__ float bf2f(short s) {
  unsigned u = ((unsigned)(unsigned short)s) << 16;
  return __builtin_bit_cast(float, u);
}
__device__ __forceinline__ short f2bf(float f) {
  return (short)__bfloat16_as_ushort(__float2bfloat16(f));
}
__device__ __forceinline__ int docof(int b, const int* __restrict__ doc_spans) {
  int cnt = 0;
  for (int dd = 0; dd < D_; dd++) cnt += (doc_spans[dd * 2] <= b) ? 1 : 0;
  return cnt - 1;
}

// -- fused: token pooling [0,N) + W transpose [N,N+1728) + zero-fill (rest) --
__global__ __launch_bounds__(256) void k_token_wt(const float* __restrict__ features,
                                                  const int* __restrict__ token_spans,
                                                  const int* __restrict__ masks,
                                                  const int* __restrict__ selidx,
                                                  __hip_bfloat16* __restrict__ h0,
                                                  const float* __restrict__ W0,
                                                  const float* __restrict__ W1,
                                                  const float* __restrict__ W2,
                                                  __hip_bfloat16* __restrict__ Wt,
                                                  int4* __restrict__ zero_base) {
  int bid = blockIdx.x;
  if (bid < N_) {
    if (threadIdx.x >= 192) return;
    int n = bid;
    int b = n / S_;
    int t = selidx[n];
    int st = token_spans[(b * T_ + t) * 2 + 0];
    int en = token_spans[(b * T_ + t) * 2 + 1];
    int tid = threadIdx.x;
    float4 a = make_float4(0.f, 0.f, 0.f, 0.f);
    int cnt = 0;
    for (int l = st; l < en; l++) {
      if (masks[b * L_ + l] > 0) {
        cnt++;
        float4 v = ((const float4*)(features + ((size_t)b * L_ + l) * H_))[tid];
        a.x += v.x; a.y += v.y; a.z += v.z; a.w += v.w;
      }
    }
    float sc = (en > 0) ? (1.0f / (float)max(cnt, 1)) : 0.0f;
    short4 o;
    o.x = f2bf(a.x * sc); o.y = f2bf(a.y * sc); o.z = f2bf(a.z * sc); o.w = f2bf(a.w * sc);
    ((short4*)(h0 + (size_t)n * H_))[tid] = o;
    return;
  }
  if (bid < N_ + NB_WT) {
    int wb = bid - N_;                     // 0..1727
    int layer = wb / 576;
    int rem = wb % 576;
    int k0 = (rem % 24) * 32, n0 = (rem / 24) * 32;
    const float* Ws[3] = {W0, W1, W2};
    const float* W = Ws[layer];
    __hip_bfloat16* O = Wt + (size_t)layer * H_ * H_;
    __shared__ float tbuf[32][33];
    int x = threadIdx.x % 32, y = threadIdx.x / 32;   // 32x8
    for (int i = 0; i < 32; i += 8)
      tbuf[y + i][x] = W[(size_t)(k0 + y + i) * H_ + n0 + x];
    __syncthreads();
    for (int i = 0; i < 32; i += 8)
      O[(size_t)(n0 + y + i) * H_ + k0 + x] = __float2bfloat16(tbuf[x][y + i]);
    return;
  }
  int zi = bid - N_ - NB_WT;
  zero_base[zi * 256 + threadIdx.x] = make_int4(0, 0, 0, 0);
}

// ---------------- CSR build (edges constant across layers) ----------------
__global__ void k_count(const int* __restrict__ dst, int* __restrict__ counts, int ne) {
  int i = blockIdx.x * 256 + threadIdx.x;
  if (i < ne) atomicAdd(&counts[dst[i]], 1);
}

__global__ __launch_bounds__(1024) void k_scan(const int* __restrict__ counts,
                                               int* __restrict__ offs,
                                               int* __restrict__ cursor) {
  __shared__ int part[1024];
  int tid = threadIdx.x;
  int base = tid * 8;
  int loc[8];
  int s = 0;
  for (int i = 0; i < 8; i++) { loc[i] = s; s += counts[base + i]; }
  part[tid] = s;
  __syncthreads();
  for (int off = 1; off < 1024; off <<= 1) {
    int v = (tid >= off) ? part[tid - off] : 0;
    __syncthreads();
    part[tid] += v;
    __syncthreads();
  }
  int excl = (tid == 0) ? 0 : part[tid - 1];
  for (int i = 0; i < 8; i++) {
    int o = excl + loc[i];
    offs[base + i] = o;
    cursor[base + i] = o;
  }
  if (tid == 1023) offs[N_] = part[1023];
}

__global__ void k_scatter(const int* __restrict__ dst, const int* __restrict__ src,
                          int* __restrict__ cursor, int* __restrict__ esrc, int ne) {
  int i = blockIdx.x * 256 + threadIdx.x;
  if (i < ne) { int p = atomicAdd(&cursor[dst[i]], 1); esrc[p] = src[i]; }
}

// ------ bf16 MFMA GEMM + fused el/er; z written as fp8 e4m3 ---------------
// 128x128 tile, BK=32, 4 waves, double-buffered LDS.
__global__ __launch_bounds__(256) void k_gemm_bf16(const __hip_bfloat16* __restrict__ A,
                                                   const __hip_bfloat16* __restrict__ Bt,
                                                   unsigned char* __restrict__ C,
                                                   const float* __restrict__ al,
                                                   const float* __restrict__ ar,
                                                   float* __restrict__ el,
                                                   float* __restrict__ er) {
  __shared__ __hip_bfloat16 As[2][128 * 32];
  __shared__ __hip_bfloat16 Bs[2][128 * 32];
  int tid = threadIdx.x;
  int bm = blockIdx.x * 128;
  int bn = blockIdx.y * 128;
  int w = tid >> 6;
  int l = tid & 63;
  int wr = w >> 1, wc = w & 1;
  int lr = l & 15;
  int lk = (l >> 4) * 8;
  f32x4 acc[4][4] = {};

  const __hip_bfloat16* gA[2];
  const __hip_bfloat16* gB[2];
  int ldsoff[2];
#pragma unroll
  for (int i = 0; i < 2; i++) {
    int idx = i * 256 + tid;
    int row = idx >> 2;
    int ck = (idx & 3) * 8;
    gA[i] = A + (size_t)(bm + row) * KDIM + ck;
    gB[i] = Bt + (size_t)(bn + row) * KDIM + ck;
    ldsoff[i] = idx * 8;
  }

  auto stage = [&](int buf, int k0) {
#pragma unroll
    for (int i = 0; i < 2; i++) GLOAD_LDS16(gA[i] + k0, &As[buf][ldsoff[i]]);
#pragma unroll
    for (int i = 0; i < 2; i++) GLOAD_LDS16(gB[i] + k0, &Bs[buf][ldsoff[i]]);
  };

  stage(0, 0);
  __syncthreads();

  constexpr int NT = KDIM / 32;          // 24 K-steps
  for (int t = 0; t < NT; t++) {
    int cur = t & 1;
    if (t < NT - 1) stage(cur ^ 1, (t + 1) * 32);
    short8v a_frag[4], b_frag[4];
#pragma unroll
    for (int m = 0; m < 4; m++)
      a_frag[m] = *(const short8v*)&As[cur][(wr * 64 + m * 16 + lr) * 32 + lk];
#pragma unroll
    for (int n = 0; n < 4; n++)
      b_frag[n] = *(const short8v*)&Bs[cur][(wc * 64 + n * 16 + lr) * 32 + lk];
#pragma unroll
    for (int m = 0; m < 4; m++)
#pragma unroll
      for (int n = 0; n < 4; n++)
        acc[m][n] = __builtin_amdgcn_mfma_f32_16x16x32_bf16(a_frag[m], b_frag[n], acc[m][n], 0, 0, 0);
    __syncthreads();
  }

  // per-lane al/ar for this block's columns: col = bn + wc*64 + n*16 + lr
  float alv[4], arv[4];
#pragma unroll
  for (int n = 0; n < 4; n++) {
    int col = bn + wc * 64 + n * 16 + lr;
    alv[n] = al[col]; arv[n] = ar[col];
  }
  // C/D layout: col = lane&15, row = (lane>>4)*4 + r  [verified m89/m91]
#pragma unroll
  for (int m = 0; m < 4; m++) {
    int rbase = bm + wr * 64 + m * 16 + (l >> 4) * 4;
#pragma unroll
    for (int n = 0; n < 4; n++) {
      int col = bn + wc * 64 + n * 16 + lr;
#pragma unroll
      for (int r = 0; r < 4; r++) {
        float v = acc[m][n][r];
        int pk = __builtin_amdgcn_cvt_pk_fp8_f32(v, v, 0, false);
        C[(size_t)(rbase + r) * H_ + col] = (unsigned char)(pk & 0xff);
      }
    }
    // fused el/er partials: reduce over the 16 lanes of each row group
#pragma unroll
    for (int r = 0; r < 4; r++) {
      float pel = 0.f, per_ = 0.f;
#pragma unroll
      for (int n = 0; n < 4; n++) {
        pel  += acc[m][n][r] * alv[n];
        per_ += acc[m][n][r] * arv[n];
      }
#pragma unroll
      for (int off2 = 1; off2 < 16; off2 <<= 1) {
        pel  += __shfl_xor(pel,  off2);
        per_ += __shfl_xor(per_, off2);
      }
      if (lr == 0) {
        atomicAdd(&el[rbase + r], pel);
        atomicAdd(&er[rbase + r], per_);
      }
    }
  }
}

// ------- wave-per-dst-node softmax + weighted agg (fp8 z) + elu -----------
__global__ __launch_bounds__(256) void k_agg(const unsigned char* __restrict__ z,
                                             const float* __restrict__ el,
                                             const float* __restrict__ er,
                                             const int* __restrict__ offs,
                                             const int* __restrict__ esrc,
                                             __hip_bfloat16* __restrict__ hout) {
  int wv = threadIdx.x >> 6, lane = threadIdx.x & 63;
  int n = blockIdx.x * 4 + wv;
  int o0 = offs[n];
  int deg = offs[n + 1] - o0;
  float ern = er[n];
  float acc[12] = {};

  if (deg <= 64) {
    float w_ = 0.f; int s_ = 0;
    if (lane < deg) {
      s_ = esrc[o0 + lane];
      float v = el[s_] + ern;
      w_ = v > 0.f ? v : NEG_SLOPE * v;
    } else {
      w_ = -1e30f;
    }
    float m = w_;
    for (int off = 32; off; off >>= 1) m = fmaxf(m, __shfl_xor(m, off));
    float ex = (lane < deg) ? __expf(w_ - m) : 0.f;
    float sum = ex;
    for (int off = 32; off; off >>= 1) sum += __shfl_xor(sum, off);
    w_ = ex / sum;
    for (int j = 0; j < deg; j++) {
      float wj = __shfl(w_, j);
      int sj = __shfl(s_, j);
      const unsigned* zr = (const unsigned*)(z + (size_t)sj * H_);
#pragma unroll
      for (int i = 0; i < 3; i++) {
        unsigned u = zr[lane + i * 64];
        acc[i * 4 + 0] += wj * __builtin_amdgcn_cvt_f32_fp8(u, 0);
        acc[i * 4 + 1] += wj * __builtin_amdgcn_cvt_f32_fp8(u, 1);
        acc[i * 4 + 2] += wj * __builtin_amdgcn_cvt_f32_fp8(u, 2);
        acc[i * 4 + 3] += wj * __builtin_amdgcn_cvt_f32_fp8(u, 3);
      }
    }
  } else {
    float lmax = -1e30f;
    for (int i = lane; i < deg; i += 64) {
      float v = el[esrc[o0 + i]] + ern;
      v = v > 0.f ? v : NEG_SLOPE * v;
      lmax = fmaxf(lmax, v);
    }
    for (int off = 32; off; off >>= 1) lmax = fmaxf(lmax, __shfl_xor(lmax, off));
    float lsum = 0.f;
    for (int i = lane; i < deg; i += 64) {
      float v = el[esrc[o0 + i]] + ern;
      v = v > 0.f ? v : NEG_SLOPE * v;
      lsum += __expf(v - lmax);
    }
    for (int off = 32; off; off >>= 1) lsum += __shfl_xor(lsum, off);
    float inv = 1.0f / lsum;
    for (int base = 0; base < deg; base += 64) {
      int chunk = min(64, deg - base);
      float w_ = 0.f; int s_ = 0;
      if (lane < chunk) {
        s_ = esrc[o0 + base + lane];
        float v = el[s_] + ern;
        v = v > 0.f ? v : NEG_SLOPE * v;
        w_ = __expf(v - lmax) * inv;
      }
      for (int j = 0; j < chunk; j++) {
        float wj = __shfl(w_, j);
        int sj = __shfl(s_, j);
        const unsigned* zr = (const unsigned*)(z + (size_t)sj * H_);
#pragma unroll
        for (int i = 0; i < 3; i++) {
          unsigned u = zr[lane + i * 64];
          acc[i * 4 + 0] += wj * __builtin_amdgcn_cvt_f32_fp8(u, 0);
          acc[i * 4 + 1] += wj * __builtin_amdgcn_cvt_f32_fp8(u, 1);
          acc[i * 4 + 2] += wj * __builtin_amdgcn_cvt_f32_fp8(u, 2);
          acc[i * 4 + 3] += wj * __builtin_amdgcn_cvt_f32_fp8(u, 3);
        }
      }
    }
  }

  short4* ho = (short4*)(hout + (size_t)n * H_);
#pragma unroll
  for (int i = 0; i < 3; i++) {
    float e0 = acc[i * 4 + 0]; e0 = e0 > 0.f ? e0 : __expf(e0) - 1.f;
    float e1 = acc[i * 4 + 1]; e1 = e1 > 0.f ? e1 : __expf(e1) - 1.f;
    float e2 = acc[i * 4 + 2]; e2 = e2 > 0.f ? e2 : __expf(e2) - 1.f;
    float e3 = acc[i * 4 + 3]; e3 = e3 > 0.f ? e3 : __expf(e3) - 1.f;
    short4 o; o.x = f2bf(e0); o.y = f2bf(e1); o.z = f2bf(e2); o.w = f2bf(e3);
    ho[lane + i * 64] = o;
  }
}

// ------- fused doc reductions: grid (B, 16): y<8 -> avg, y>=8 -> qf -------
__global__ __launch_bounds__(192) void k_avgqf(const __hip_bfloat16* __restrict__ h,
                                               const float* __restrict__ features,
                                               const int* __restrict__ masks,
                                               const int* __restrict__ segment_ids,
                                               const int* __restrict__ is_head,
                                               const int* __restrict__ doc_spans,
                                               float* __restrict__ avgp,
                                               float* __restrict__ qfp) {
  int b = blockIdx.x;
  int y = blockIdx.y;
  int tid = threadIdx.x;
  int d = docof(b, doc_spans);
  if (y < 8) {
    int s0 = y * 16;
    float4 a = make_float4(0.f, 0.f, 0.f, 0.f);
    for (int i = 0; i < 16; i++) {
      short4 v = ((const short4*)(h + ((size_t)(b * S_ + s0 + i)) * H_))[tid];
      a.x += bf2f(v.x); a.y += bf2f(v.y); a.z += bf2f(v.z); a.w += bf2f(v.w);
    }
    atomicAdd(&avgp[d * H_ + tid * 4 + 0], a.x);
    atomicAdd(&avgp[d * H_ + tid * 4 + 1], a.y);
    atomicAdd(&avgp[d * H_ + tid * 4 + 2], a.z);
    atomicAdd(&avgp[d * H_ + tid * 4 + 3], a.w);
  } else {
    int l0 = (y - 8) * 64;
    __shared__ float qm[64];
    if (tid < 64) {
      int l = l0 + tid;
      qm[tid] = (is_head[b * L_ + l] != 2 && segment_ids[b * L_ + l] == 0 && masks[b * L_ + l] > 0) ? 1.0f : 0.0f;
    }
    __syncthreads();
    float4 a = make_float4(0.f, 0.f, 0.f, 0.f);
    for (int i = 0; i < 64; i++) {
      if (qm[i] != 0.f) {
        float4 v = ((const float4*)(features + ((size_t)b * L_ + l0 + i) * H_))[tid];
        a.x += v.x; a.y += v.y; a.z += v.z; a.w += v.w;
      }
    }
    atomicAdd(&qfp[d * H_ + tid * 4 + 0], a.x);
    atomicAdd(&qfp[d * H_ + tid * 4 + 1], a.y);
    atomicAdd(&qfp[d * H_ + tid * 4 + 2], a.z);
    atomicAdd(&qfp[d * H_ + tid * 4 + 3], a.w);
  }
}

// ---------------- final: out[d] = sum_h |qf/doccnt - avg/nodecnt| ----------
__global__ __launch_bounds__(512) void k_final(const float* __restrict__ qfp,
                                               const float* __restrict__ avgp,
                                               const int* __restrict__ doc_spans,
                                               float* __restrict__ out) {
  __shared__ int ds[D_ * 2];
  int tid = threadIdx.x;
  if (tid < D_ * 2) ds[tid] = doc_spans[tid];
  __syncthreads();
  int d = tid >> 6, lane = tid & 63;
  int nsent = 0;
  for (int b = 0; b < B_; b++) {
    int cnt = 0;
#pragma unroll
    for (int dd = 0; dd < D_; dd++) cnt += (ds[dd * 2] <= b) ? 1 : 0;
    nsent += ((cnt - 1) == d) ? 1 : 0;
  }
  float inv_node = 1.0f / fmaxf((float)nsent * (float)S_, 1.0f);
  float inv_doc  = 1.0f / fmaxf((float)(ds[d * 2 + 1] - ds[d * 2]), 1.0f);
  float acc = 0.f;
  for (int h = lane; h < H_; h += 64)
    acc += fabsf(qfp[d * H_ + h] * inv_doc - avgp[d * H_ + h] * inv_node);
  for (int off = 32; off; off >>= 1) acc += __shfl_xor(acc, off);
  if (lane == 0) out[d] = acc;
}

extern "C" void kernel_launch(void* const* d_in, const int* in_sizes, int n_in,
                              void* d_out, int out_size, void* d_ws, size_t ws_size,
                              hipStream_t stream) {
  const float* features     = (const float*)d_in[0];
  const int*   token_spans  = (const int*)d_in[1];
  const int*   masks        = (const int*)d_in[2];
  const int*   selidx       = (const int*)d_in[3];
  const int*   src          = (const int*)d_in[4];
  const int*   dst          = (const int*)d_in[5];
  const int*   doc_spans    = (const int*)d_in[6];
  const int*   segment_ids  = (const int*)d_in[7];
  const int*   is_head      = (const int*)d_in[8];
  const float* Wl[3]  = {(const float*)d_in[9],  (const float*)d_in[12], (const float*)d_in[15]};
  const float* alv[3] = {(const float*)d_in[10], (const float*)d_in[13], (const float*)d_in[16]};
  const float* arv[3] = {(const float*)d_in[11], (const float*)d_in[14], (const float*)d_in[17]};
  float* out = (float*)d_out;

  char* ws = (char*)d_ws;
  size_t off = 0;
  auto alloc = [&](size_t bytes) -> void* {
    void* p = ws + off;
    off = (off + bytes + 255) & ~(size_t)255;
    return p;
  };
  __hip_bfloat16* hA = (__hip_bfloat16*)alloc((size_t)N_ * H_ * 2);   // bf16 h
  unsigned char*  hB = (unsigned char*)alloc((size_t)N_ * H_);        // fp8 z
  __hip_bfloat16* Wt = (__hip_bfloat16*)alloc((size_t)3 * H_ * H_ * 2);
  // ---- contiguous zero-fill region: avgp|qfp | el[3] | er[3] | counts ----
  float* avgp   = (float*)alloc((size_t)2 * D_ * H_ * 4);  // avgp | qfp
  float* qfp    = avgp + (size_t)D_ * H_;
  float* el     = (float*)alloc((size_t)3 * N_ * 4);
  float* er     = (float*)alloc((size_t)3 * N_ * 4);
  int*   counts = (int*)alloc((size_t)N_ * 4);
  // total = (2*8*768 + 6*8192 + 8192)*4 = 278528 B = 68 blocks * 256 * 16 B
  int*   offs   = (int*)alloc((size_t)(N_ + 1) * 4);
  int*   cursor = (int*)alloc((size_t)N_ * 4);
  int*   esrc   = (int*)alloc((size_t)NE_ * 4);

  // token pooling + W transposes + zero-fill in one dispatch (runs FIRST:
  // zeroes counts before k_count, el/er before gemm, avgp/qfp before avgqf)
  k_token_wt<<<N_ + NB_WT + NB_ZERO, 256, 0, stream>>>(features, token_spans, masks, selidx,
                                                       hA, Wl[0], Wl[1], Wl[2], Wt,
                                                       (int4*)avgp);

  // CSR build (edges constant across layers)
  k_count<<<(NE_ + 255) / 256, 256, 0, stream>>>(dst, counts, NE_);
  k_scan<<<1, 1024, 0, stream>>>(counts, offs, cursor);
  k_scatter<<<(NE_ + 255) / 256, 256, 0, stream>>>(dst, src, cursor, esrc, NE_);

  // 3 GAT layers: hA(bf16) -> z(hB,fp8)+el/er -> hA(bf16)
  for (int i = 0; i < 3; i++) {
    k_gemm_bf16<<<dim3(N_ / 128, H_ / 128), 256, 0, stream>>>(
        hA, Wt + (size_t)i * H_ * H_, hB, alv[i], arv[i],
        el + (size_t)i * N_, er + (size_t)i * N_);
    k_agg<<<N_ / 4, 256, 0, stream>>>(hB, el + (size_t)i * N_, er + (size_t)i * N_,
                                      offs, esrc, hA);
  }

  // doc-level reductions (avg + qf fused)
  k_avgqf<<<dim3(B_, 16), 192, 0, stream>>>(hA, features, masks, segment_ids, is_head,
                                            doc_spans, avgp, qfp);
  k_final<<<1, 512, 0, stream>>>(qfp, avgp, doc_spans, out);
}